// Round 13
// baseline (16506.680 us; speedup 1.0000x reference)
//
#include <hip/hip_runtime.h>
#include <hip/hip_bf16.h>

#define TT 2048
#define HH 1024
#define GH 4096

__device__ __forceinline__ float sigm(float x){ return 1.0f / (1.0f + __expf(-x)); }

// -------- Phase 1: plain fp32 tiled GEMM (validated r3-r11) --------
#define BM 128
#define BN 64
#define BK 32

__global__ __launch_bounds__(256) void gemm_simple(
    const int* __restrict__ tokens,
    const float* __restrict__ emb,
    const float* __restrict__ Wih,
    const float* __restrict__ bih,
    const float* __restrict__ bhh,
    float* __restrict__ gx)
{
  __shared__ float As[BM][BK+1];
  __shared__ float Bs[BN][BK+1];
  __shared__ int tok_s[BM];

  const int tid = threadIdx.x;
  const int bn = blockIdx.x;
  const int bm = blockIdx.y;
  const int m0 = bm*BM, n0 = bn*BN;

  if (tid < BM) tok_s[tid] = tokens[m0 + tid];
  __syncthreads();

  const int tm = tid >> 4;
  const int tn = tid & 15;

  float acc[8][4];
  #pragma unroll
  for (int i = 0; i < 8; ++i)
    #pragma unroll
    for (int j = 0; j < 4; ++j) acc[i][j] = 0.0f;

  for (int k0 = 0; k0 < HH; k0 += BK) {
    for (int idx = tid; idx < BM*BK; idx += 256) {
      int r = idx >> 5, c = idx & 31;
      As[r][c] = emb[(size_t)tok_s[r]*HH + k0 + c];
    }
    for (int idx = tid; idx < BN*BK; idx += 256) {
      int r = idx >> 5, c = idx & 31;
      Bs[r][c] = Wih[(size_t)(n0 + r)*HH + k0 + c];
    }
    __syncthreads();
    #pragma unroll
    for (int k = 0; k < BK; ++k) {
      float a[8], bb[4];
      #pragma unroll
      for (int i = 0; i < 8; ++i) a[i] = As[tm*8 + i][k];
      #pragma unroll
      for (int j = 0; j < 4; ++j) bb[j] = Bs[tn*4 + j][k];
      #pragma unroll
      for (int i = 0; i < 8; ++i)
        #pragma unroll
        for (int j = 0; j < 4; ++j)
          acc[i][j] = fmaf(a[i], bb[j], acc[i][j]);
    }
    __syncthreads();
  }

  float bias[4];
  #pragma unroll
  for (int j = 0; j < 4; ++j) {
    int col = n0 + tn*4 + j;
    bias[j] = bih[col] + bhh[col];
  }
  #pragma unroll
  for (int i = 0; i < 8; ++i) {
    int r = m0 + tm*8 + i;
    #pragma unroll
    for (int j = 0; j < 4; ++j)
      gx[(size_t)r*GH + (n0 + tn*4 + j)] = acc[i][j] + bias[j];
  }
}

// -------- Phase 2: persistent scan, LDS-resident weights (r12 fixed) --------
// 342 blocks x 4 waves (3 compute + 1 listener), 3 outputs/block.
// wlds layout (floats): (((oL*4 + g)*4 + q)*64 + lane)*4 + e  == 12288 floats (48KB).
//   holds Whh[g*1024 + (b*3+oL)][64*(4q+e) + lane];  float4 read covers e=0..3.
// hbuf: 8KB double buffer filled by listener polling the 1024 slots.
// One barrier/step. 2-parity ping-pong race-free (r11 chain argument).
#define NBLK 342
#define STH 256

__global__ __launch_bounds__(STH) void lstm_scan(
    const float* __restrict__ gx,
    const float* __restrict__ Whh,
    unsigned long long* slots,     // [2][1024] {tag<<32 | fp32 h}
    float* __restrict__ out)       // [2048] fp32 = h ; c
{
  const int b    = blockIdx.x;
  const int tid  = threadIdx.x;
  const int lane = tid & 63;
  const int wv   = tid >> 6;          // 0..3
  const int o    = b*3 + wv;          // owned output (compute waves)
  const bool isCompute  = (wv < 3) && (o < 1024);
  const bool isListener = (wv == 3);

  __shared__ float wlds[12288];       // 48 KB
  __shared__ float hbuf[2][1024];     // 8 KB

  // ---- stage weights (once) ----
  #pragma unroll
  for (int rr = 0; rr < 12; ++rr) {
    const int oLw = rr >> 2, g = rr & 3;
    const int oG = b*3 + oLw;
    if (oG < 1024) {
      const float* row = Whh + (size_t)((g << 10) + oG) * HH;
      for (int j = tid; j < 1024; j += STH) {
        const int l = j & 63, m = j >> 6;         // m = 4q+e, q=m>>2, e=m&3
        wlds[(((oLw*4 + g)*4 + (m >> 2))*64 + l)*4 + (m & 3)] = row[j];
      }
    }
  }
  for (int i = tid; i < 1024; i += STH) hbuf[0][i] = 0.0f;   // h(0)=0

  float cst = 0.0f;
  float g4[4] = {0.f, 0.f, 0.f, 0.f};
  if (isCompute) {
    #pragma unroll
    for (int g = 0; g < 4; ++g) g4[g] = gx[(g << 10) + o];   // t=0
  }
  __syncthreads();

  const float4* wf4 = (const float4*)wlds;   // index: ((oL*4+g)*4 + q)*64 + lane

  for (int t = 0; t < TT; ++t) {
    const int cur = t & 1, nxt = cur ^ 1;

    if (isListener) {
      if (t < TT-1) {                 // gather h(t+1) into hbuf[nxt]
        const unsigned long long* sb = slots + (size_t)nxt * 1024;
        const unsigned tg = (unsigned)(t+1);
        unsigned long long v[16];
        #pragma unroll
        for (int j = 0; j < 16; ++j)
          v[j] = __hip_atomic_load(&sb[lane + 64*j], __ATOMIC_RELAXED, __HIP_MEMORY_SCOPE_AGENT);
        #pragma unroll
        for (int j = 0; j < 16; ++j)
          while ((unsigned)(v[j] >> 32) != tg)
            v[j] = __hip_atomic_load(&sb[lane + 64*j], __ATOMIC_RELAXED, __HIP_MEMORY_SCOPE_AGENT);
        #pragma unroll
        for (int j = 0; j < 16; ++j)
          hbuf[nxt][64*j + lane] = __uint_as_float((unsigned)v[j]);
      }
    } else if (isCompute) {
      float ng[4] = {0.f, 0.f, 0.f, 0.f};
      if (t + 1 < TT) {
        #pragma unroll
        for (int g = 0; g < 4; ++g)     // prefetch next gx under this step
          ng[g] = gx[(size_t)(t+1)*GH + (g << 10) + o];
      }

      float h[16];
      #pragma unroll
      for (int m = 0; m < 16; ++m) h[m] = hbuf[cur][64*m + lane];

      float a0 = 0.f, a1 = 0.f, a2 = 0.f, a3 = 0.f;
      #pragma unroll
      for (int q = 0; q < 4; ++q) {
        const float4 w0 = wf4[((wv*4 + 0)*4 + q)*64 + lane];
        const float4 w1 = wf4[((wv*4 + 1)*4 + q)*64 + lane];
        const float4 w2 = wf4[((wv*4 + 2)*4 + q)*64 + lane];
        const float4 w3 = wf4[((wv*4 + 3)*4 + q)*64 + lane];
        const float h0 = h[4*q+0], h1 = h[4*q+1], h2 = h[4*q+2], h3 = h[4*q+3];
        a0 = fmaf(w0.x, h0, a0); a0 = fmaf(w0.y, h1, a0);
        a0 = fmaf(w0.z, h2, a0); a0 = fmaf(w0.w, h3, a0);
        a1 = fmaf(w1.x, h0, a1); a1 = fmaf(w1.y, h1, a1);
        a1 = fmaf(w1.z, h2, a1); a1 = fmaf(w1.w, h3, a1);
        a2 = fmaf(w2.x, h0, a2); a2 = fmaf(w2.y, h1, a2);
        a2 = fmaf(w2.z, h2, a2); a2 = fmaf(w2.w, h3, a2);
        a3 = fmaf(w3.x, h0, a3); a3 = fmaf(w3.y, h1, a3);
        a3 = fmaf(w3.z, h2, a3); a3 = fmaf(w3.w, h3, a3);
      }

      // folded butterfly: lane l ends holding full sum of gate (l&3)
      float acc[4] = {a0, a1, a2, a3};
      float v2[2];
      #pragma unroll
      for (int i = 0; i < 2; ++i) {
        float a = (lane & 1) ? acc[2*i+1] : acc[2*i];
        float qq = (lane & 1) ? acc[2*i]   : acc[2*i+1];
        v2[i] = a + __shfl_xor(qq, 1);
      }
      float v1;
      {
        float a = (lane & 2) ? v2[1] : v2[0];
        float qq = (lane & 2) ? v2[0] : v2[1];
        v1 = a + __shfl_xor(qq, 2);
      }
      v1 += __shfl_xor(v1, 4);
      v1 += __shfl_xor(v1, 8);
      v1 += __shfl_xor(v1, 16);
      v1 += __shfl_xor(v1, 32);

      float xi = __shfl(v1, 0) + g4[0];
      float xf = __shfl(v1, 1) + g4[1];
      float xg = __shfl(v1, 2) + g4[2];
      float xo = __shfl(v1, 3) + g4[3];

      cst = sigm(xf)*cst + sigm(xi)*tanhf(xg);
      float hnew = sigm(xo)*tanhf(cst);

      if (t == TT-1) {
        if (lane == 0) {
          out[o]        = hnew;
          out[1024 + o] = cst;
        }
      } else {
        if (lane == 0) {
          unsigned long long pv =
              (((unsigned long long)(unsigned)(t+1)) << 32) |
              (unsigned long long)__float_as_uint(hnew);
          __hip_atomic_store(&slots[(size_t)nxt*1024 + o], pv,
                             __ATOMIC_RELAXED, __HIP_MEMORY_SCOPE_AGENT);
        }
        #pragma unroll
        for (int g = 0; g < 4; ++g) g4[g] = ng[g];
      }
    }
    __syncthreads();
  }
}

// fallback: ws too small -> zeros
__global__ void zero_out(float* out){
  int i = blockIdx.x*256 + threadIdx.x;
  if (i < 2048) out[i] = 0.0f;
}

extern "C" void kernel_launch(void* const* d_in, const int* in_sizes, int n_in,
                              void* d_out, int out_size, void* d_ws, size_t ws_size,
                              hipStream_t stream) {
  (void)in_sizes; (void)n_in; (void)out_size;
  const int* tokens = (const int*)d_in[0];
  const float* emb  = (const float*)d_in[1];
  const float* Wih  = (const float*)d_in[2];
  const float* Whh  = (const float*)d_in[3];
  const float* bih  = (const float*)d_in[4];
  const float* bhh  = (const float*)d_in[5];
  float* out = (float*)d_out;

  // ws: [0,16K) slots[2][1024] u64 | [16K, ...) gx fp32 [2048][4096]
  unsigned long long* slots = (unsigned long long*)d_ws;
  float* gx = (float*)((char*)d_ws + 16384);
  const size_t needF32 = 16384 + (size_t)TT*GH*sizeof(float);

  hipMemsetAsync(slots, 0, 16384, stream);
  if (ws_size >= needF32) {
    gemm_simple<<<dim3(64,16), dim3(256), 0, stream>>>(tokens, emb, Wih, bih, bhh, gx);
    lstm_scan<<<dim3(NBLK), dim3(STH), 0, stream>>>(gx, Whh, slots, out);
  } else {
    zero_out<<<dim3(8), dim3(256), 0, stream>>>(out);
  }
}

// Round 14
// 7001.724 us; speedup vs baseline: 2.3575x; 2.3575x over previous
//
#include <hip/hip_runtime.h>
#include <hip/hip_bf16.h>

#define TT 2048
#define HH 1024
#define GH 4096

__device__ __forceinline__ float sigm(float x){ return 1.0f / (1.0f + __expf(-x)); }
__device__ __forceinline__ float bflo(unsigned v){ return __uint_as_float(v << 16); }
__device__ __forceinline__ float bfhi(unsigned v){ return __uint_as_float(v & 0xffff0000u); }
__device__ __forceinline__ unsigned short f2bu(float x){
  __hip_bfloat16 b = __float2bfloat16(x);
  return *reinterpret_cast<unsigned short*>(&b);
}

// -------- Phase 1: plain fp32 tiled GEMM (validated r3-r13) --------
#define BM 128
#define BN 64
#define BK 32

__global__ __launch_bounds__(256) void gemm_simple(
    const int* __restrict__ tokens,
    const float* __restrict__ emb,
    const float* __restrict__ Wih,
    const float* __restrict__ bih,
    const float* __restrict__ bhh,
    float* __restrict__ gx)
{
  __shared__ float As[BM][BK+1];
  __shared__ float Bs[BN][BK+1];
  __shared__ int tok_s[BM];

  const int tid = threadIdx.x;
  const int bn = blockIdx.x;
  const int bm = blockIdx.y;
  const int m0 = bm*BM, n0 = bn*BN;

  if (tid < BM) tok_s[tid] = tokens[m0 + tid];
  __syncthreads();

  const int tm = tid >> 4;
  const int tn = tid & 15;

  float acc[8][4];
  #pragma unroll
  for (int i = 0; i < 8; ++i)
    #pragma unroll
    for (int j = 0; j < 4; ++j) acc[i][j] = 0.0f;

  for (int k0 = 0; k0 < HH; k0 += BK) {
    for (int idx = tid; idx < BM*BK; idx += 256) {
      int r = idx >> 5, c = idx & 31;
      As[r][c] = emb[(size_t)tok_s[r]*HH + k0 + c];
    }
    for (int idx = tid; idx < BN*BK; idx += 256) {
      int r = idx >> 5, c = idx & 31;
      Bs[r][c] = Wih[(size_t)(n0 + r)*HH + k0 + c];
    }
    __syncthreads();
    #pragma unroll
    for (int k = 0; k < BK; ++k) {
      float a[8], bb[4];
      #pragma unroll
      for (int i = 0; i < 8; ++i) a[i] = As[tm*8 + i][k];
      #pragma unroll
      for (int j = 0; j < 4; ++j) bb[j] = Bs[tn*4 + j][k];
      #pragma unroll
      for (int i = 0; i < 8; ++i)
        #pragma unroll
        for (int j = 0; j < 4; ++j)
          acc[i][j] = fmaf(a[i], bb[j], acc[i][j]);
    }
    __syncthreads();
  }

  float bias[4];
  #pragma unroll
  for (int j = 0; j < 4; ++j) {
    int col = n0 + tn*4 + j;
    bias[j] = bih[col] + bhh[col];
  }
  #pragma unroll
  for (int i = 0; i < 8; ++i) {
    int r = m0 + tm*8 + i;
    #pragma unroll
    for (int j = 0; j < 4; ++j)
      gx[(size_t)r*GH + (n0 + tn*4 + j)] = acc[i][j] + bias[j];
  }
}

// -------- Phase 2 primary: r7-champion structure + bf16 weights in dynamic LDS --------
// 64 blocks x 512 thr. Each thread polls 2 slots (64K loads/iter chip-wide — the
// measured-optimal poll footprint). h via LDS, 2 barriers/step, publish by tid<8.
// Weights: 64 rows (row = g*16+oL) x 1024 bf16 in 128.5KB dynamic LDS,
// [j2][s]-interleaved b64 units (+1 unit/row pad): conflict-free ds_read_b64.
#define GBLK 64
#define NTH 512
#define HSTRIDE 130
#define ROWU 257          // b64 units per row (256 + 1 pad)

__global__ __launch_bounds__(NTH) void lstm_scan_lds(
    const float* __restrict__ gx,
    const float* __restrict__ Whh,
    unsigned long long* slots,     // [2][1024] {tag<<32 | fp32 h}
    float* __restrict__ out)       // [2048] fp32 = h ; c
{
  extern __shared__ __align__(16) unsigned wdw[];   // 64*ROWU*2 dwords (bf16 weights)
  __shared__ float h_lds[32*HSTRIDE];
  __shared__ float gates_lds[64];

  const int b = blockIdx.x;
  const int tid = threadIdx.x;
  const int s  = tid & 31;   // col segment (32 cols each)
  const int rg = tid >> 5;   // row group (rows rg*4 .. rg*4+3)

  // ---- stage weights once: row r -> Whh[(r>>4)*1024 + b*16 + (r&15)] ----
  for (int r = 0; r < 64; ++r) {
    const int jrow = ((r >> 4) << 10) + (b << 4) + (r & 15);
    const int c0 = tid * 2;
    const float2 f2 = *(const float2*)(Whh + (size_t)jrow*HH + c0);
    const unsigned pk = (unsigned)f2bu(f2.x) | ((unsigned)f2bu(f2.y) << 16);
    const int sT = c0 >> 5, j2 = (c0 & 31) >> 2, d = (c0 >> 1) & 1;
    wdw[r*(2*ROWU) + (j2*32 + sT)*2 + d] = pk;
  }

  for (int i = tid; i < 32*HSTRIDE; i += NTH) h_lds[i] = 0.0f;   // h(0)=0
  float c0s = 0.0f, c1s = 0.0f;                                  // c state (tid<8)
  const int i0 = tid, i1 = tid + 512;
  const int p0 = (i0 >> 5)*HSTRIDE + (i0 & 31);
  const int p1 = (i1 >> 5)*HSTRIDE + (i1 & 31);
  const int myrow = rg*4 + s;                                    // valid for s<4
  const int myj = ((myrow >> 4) << 10) + (b << 4) + (myrow & 15);
  __syncthreads();

  const uint2* wld2 = (const uint2*)wdw;

  for (int t = 0; t < TT; ++t) {
    float gxv = 0.0f;
    if (s < 4) gxv = gx[(size_t)t*GH + myj];     // in-step prefetch

    if (t > 0) {
      const unsigned long long* sb = slots + (size_t)(t & 1)*1024;
      const unsigned tg = (unsigned)t;
      unsigned long long v0 = __hip_atomic_load(&sb[i0], __ATOMIC_RELAXED, __HIP_MEMORY_SCOPE_AGENT);
      unsigned long long v1 = __hip_atomic_load(&sb[i1], __ATOMIC_RELAXED, __HIP_MEMORY_SCOPE_AGENT);
      while ((unsigned)(v0 >> 32) != tg)
        v0 = __hip_atomic_load(&sb[i0], __ATOMIC_RELAXED, __HIP_MEMORY_SCOPE_AGENT);
      while ((unsigned)(v1 >> 32) != tg)
        v1 = __hip_atomic_load(&sb[i1], __ATOMIC_RELAXED, __HIP_MEMORY_SCOPE_AGENT);
      h_lds[p0] = __uint_as_float((unsigned)v0);
      h_lds[p1] = __uint_as_float((unsigned)v1);
      __syncthreads();
    }

    float acc0 = 0.f, acc1 = 0.f, acc2 = 0.f, acc3 = 0.f;
    const float* hseg = h_lds + s*HSTRIDE;
    #pragma unroll
    for (int j2 = 0; j2 < 8; ++j2) {
      const float2 hA = *(const float2*)(hseg + 4*j2);
      const float2 hB = *(const float2*)(hseg + 4*j2 + 2);
      const uint2 w0 = wld2[(rg*4 + 0)*ROWU + j2*32 + s];
      const uint2 w1 = wld2[(rg*4 + 1)*ROWU + j2*32 + s];
      const uint2 w2 = wld2[(rg*4 + 2)*ROWU + j2*32 + s];
      const uint2 w3 = wld2[(rg*4 + 3)*ROWU + j2*32 + s];
      acc0 = fmaf(bflo(w0.x), hA.x, acc0); acc0 = fmaf(bfhi(w0.x), hA.y, acc0);
      acc0 = fmaf(bflo(w0.y), hB.x, acc0); acc0 = fmaf(bfhi(w0.y), hB.y, acc0);
      acc1 = fmaf(bflo(w1.x), hA.x, acc1); acc1 = fmaf(bfhi(w1.x), hA.y, acc1);
      acc1 = fmaf(bflo(w1.y), hB.x, acc1); acc1 = fmaf(bfhi(w1.y), hB.y, acc1);
      acc2 = fmaf(bflo(w2.x), hA.x, acc2); acc2 = fmaf(bfhi(w2.x), hA.y, acc2);
      acc2 = fmaf(bflo(w2.y), hB.x, acc2); acc2 = fmaf(bfhi(w2.y), hB.y, acc2);
      acc3 = fmaf(bflo(w3.x), hA.x, acc3); acc3 = fmaf(bfhi(w3.x), hA.y, acc3);
      acc3 = fmaf(bflo(w3.y), hB.x, acc3); acc3 = fmaf(bfhi(w3.y), hB.y, acc3);
    }
    #pragma unroll
    for (int m = 1; m <= 16; m <<= 1) {
      acc0 += __shfl_xor(acc0, m);
      acc1 += __shfl_xor(acc1, m);
      acc2 += __shfl_xor(acc2, m);
      acc3 += __shfl_xor(acc3, m);
    }
    if (s < 4) {
      float v = acc0;
      if (s == 1) v = acc1; else if (s == 2) v = acc2; else if (s == 3) v = acc3;
      gates_lds[rg*4 + s] = v + gxv;
    }
    __syncthreads();

    if (tid < 8) {
      int n0 = tid*2, n1 = n0 + 1;
      float xi0 = gates_lds[n0],    xi1 = gates_lds[n1];
      float xf0 = gates_lds[16+n0], xf1 = gates_lds[16+n1];
      float xg0 = gates_lds[32+n0], xg1 = gates_lds[32+n1];
      float xo0 = gates_lds[48+n0], xo1 = gates_lds[48+n1];
      c0s = sigm(xf0)*c0s + sigm(xi0)*tanhf(xg0);
      c1s = sigm(xf1)*c1s + sigm(xi1)*tanhf(xg1);
      float h0 = sigm(xo0)*tanhf(c0s);
      float h1 = sigm(xo1)*tanhf(c1s);
      if (t == TT-1) {
        out[(b<<4)+n0]      = h0;
        out[(b<<4)+n1]      = h1;
        out[1024+(b<<4)+n0] = c0s;
        out[1024+(b<<4)+n1] = c1s;
      } else {
        unsigned long long* db = slots + (size_t)((t+1)&1)*1024;
        unsigned long long tg = ((unsigned long long)(unsigned)(t+1)) << 32;
        __hip_atomic_store(&db[(b<<4)+n0], tg | (unsigned long long)__float_as_uint(h0),
                           __ATOMIC_RELAXED, __HIP_MEMORY_SCOPE_AGENT);
        __hip_atomic_store(&db[(b<<4)+n1], tg | (unsigned long long)__float_as_uint(h1),
                           __ATOMIC_RELAXED, __HIP_MEMORY_SCOPE_AGENT);
      }
    }
  }
}

// -------- Phase 2 fallback: exact r7 champion (weights spilled, 2.96us/step) --------
__global__ __launch_bounds__(NTH, 2) void lstm_scan_reg(
    const float* __restrict__ gx,
    const float* __restrict__ Whh,
    unsigned long long* slots,
    float* __restrict__ out)
{
  const int b = blockIdx.x;
  const int tid = threadIdx.x;
  const int s  = tid & 31;
  const int rg = tid >> 5;

  __shared__ float h_lds[32*HSTRIDE];
  __shared__ float gates_lds[64];

  float w[128];
  #pragma unroll
  for (int a = 0; a < 4; ++a) {
    int row = rg*4 + a;
    int jrow = ((row >> 4) << 10) + (b << 4) + (row & 15);
    const float* wr = Whh + (size_t)jrow*HH + s*32;
    #pragma unroll
    for (int q = 0; q < 8; ++q) {
      float4 f4 = ((const float4*)wr)[q];
      w[a*32 + q*4 + 0] = f4.x; w[a*32 + q*4 + 1] = f4.y;
      w[a*32 + q*4 + 2] = f4.z; w[a*32 + q*4 + 3] = f4.w;
    }
  }

  for (int i = tid; i < 32*HSTRIDE; i += NTH) h_lds[i] = 0.0f;
  float c0 = 0.0f, c1 = 0.0f;
  const int i0 = tid, i1 = tid + 512;
  const int p0 = (i0 >> 5)*HSTRIDE + (i0 & 31);
  const int p1 = (i1 >> 5)*HSTRIDE + (i1 & 31);
  const int myrow = rg*4 + s;
  const int myj = ((myrow >> 4) << 10) + (b << 4) + (myrow & 15);
  __syncthreads();

  for (int t = 0; t < TT; ++t) {
    float gxv = 0.0f;
    if (s < 4) gxv = gx[(size_t)t*GH + myj];

    if (t > 0) {
      const unsigned long long* sb = slots + (size_t)(t & 1)*1024;
      const unsigned tg = (unsigned)t;
      unsigned long long v0 = __hip_atomic_load(&sb[i0], __ATOMIC_RELAXED, __HIP_MEMORY_SCOPE_AGENT);
      unsigned long long v1 = __hip_atomic_load(&sb[i1], __ATOMIC_RELAXED, __HIP_MEMORY_SCOPE_AGENT);
      while ((unsigned)(v0 >> 32) != tg)
        v0 = __hip_atomic_load(&sb[i0], __ATOMIC_RELAXED, __HIP_MEMORY_SCOPE_AGENT);
      while ((unsigned)(v1 >> 32) != tg)
        v1 = __hip_atomic_load(&sb[i1], __ATOMIC_RELAXED, __HIP_MEMORY_SCOPE_AGENT);
      h_lds[p0] = __uint_as_float((unsigned)v0);
      h_lds[p1] = __uint_as_float((unsigned)v1);
      __syncthreads();
    }

    float acc0 = 0.f, acc1 = 0.f, acc2 = 0.f, acc3 = 0.f;
    const float* hseg = h_lds + s*HSTRIDE;
    #pragma unroll
    for (int c2 = 0; c2 < 16; ++c2) {
      float2 hv = *(const float2*)(hseg + 2*c2);
      acc0 = fmaf(w[0*32+2*c2], hv.x, acc0); acc0 = fmaf(w[0*32+2*c2+1], hv.y, acc0);
      acc1 = fmaf(w[1*32+2*c2], hv.x, acc1); acc1 = fmaf(w[1*32+2*c2+1], hv.y, acc1);
      acc2 = fmaf(w[2*32+2*c2], hv.x, acc2); acc2 = fmaf(w[2*32+2*c2+1], hv.y, acc2);
      acc3 = fmaf(w[3*32+2*c2], hv.x, acc3); acc3 = fmaf(w[3*32+2*c2+1], hv.y, acc3);
    }
    #pragma unroll
    for (int m = 1; m <= 16; m <<= 1) {
      acc0 += __shfl_xor(acc0, m);
      acc1 += __shfl_xor(acc1, m);
      acc2 += __shfl_xor(acc2, m);
      acc3 += __shfl_xor(acc3, m);
    }
    if (s < 4) {
      float v = acc0;
      if (s == 1) v = acc1; else if (s == 2) v = acc2; else if (s == 3) v = acc3;
      gates_lds[rg*4 + s] = v + gxv;
    }
    __syncthreads();

    if (tid < 8) {
      int n0 = tid*2, n1 = n0 + 1;
      float xi0 = gates_lds[n0],    xi1 = gates_lds[n1];
      float xf0 = gates_lds[16+n0], xf1 = gates_lds[16+n1];
      float xg0 = gates_lds[32+n0], xg1 = gates_lds[32+n1];
      float xo0 = gates_lds[48+n0], xo1 = gates_lds[48+n1];
      c0 = sigm(xf0)*c0 + sigm(xi0)*tanhf(xg0);
      c1 = sigm(xf1)*c1 + sigm(xi1)*tanhf(xg1);
      float h0 = sigm(xo0)*tanhf(c0);
      float h1 = sigm(xo1)*tanhf(c1);
      if (t == TT-1) {
        out[(b<<4)+n0]      = h0;
        out[(b<<4)+n1]      = h1;
        out[1024+(b<<4)+n0] = c0;
        out[1024+(b<<4)+n1] = c1;
      } else {
        unsigned long long* db = slots + (size_t)((t+1)&1)*1024;
        unsigned long long tg = ((unsigned long long)(unsigned)(t+1)) << 32;
        __hip_atomic_store(&db[(b<<4)+n0], tg | (unsigned long long)__float_as_uint(h0),
                           __ATOMIC_RELAXED, __HIP_MEMORY_SCOPE_AGENT);
        __hip_atomic_store(&db[(b<<4)+n1], tg | (unsigned long long)__float_as_uint(h1),
                           __ATOMIC_RELAXED, __HIP_MEMORY_SCOPE_AGENT);
      }
    }
  }
}

__global__ void zero_out(float* out){
  int i = blockIdx.x*256 + threadIdx.x;
  if (i < 2048) out[i] = 0.0f;
}

extern "C" void kernel_launch(void* const* d_in, const int* in_sizes, int n_in,
                              void* d_out, int out_size, void* d_ws, size_t ws_size,
                              hipStream_t stream) {
  (void)in_sizes; (void)n_in; (void)out_size;
  const int* tokens = (const int*)d_in[0];
  const float* emb  = (const float*)d_in[1];
  const float* Wih  = (const float*)d_in[2];
  const float* Whh  = (const float*)d_in[3];
  const float* bih  = (const float*)d_in[4];
  const float* bhh  = (const float*)d_in[5];
  float* out = (float*)d_out;

  unsigned long long* slots = (unsigned long long*)d_ws;
  float* gx = (float*)((char*)d_ws + 16384);
  const size_t needF32 = 16384 + (size_t)TT*GH*sizeof(float);

  hipMemsetAsync(slots, 0, 16384, stream);
  if (ws_size >= needF32) {
    gemm_simple<<<dim3(64,16), dim3(256), 0, stream>>>(tokens, emb, Wih, bih, bhh, gx);
    const int dynBytes = 64 * (2*ROWU) * 4;   // 131584 B bf16 weight store
    hipError_t e = hipFuncSetAttribute((const void*)lstm_scan_lds,
                                       hipFuncAttributeMaxDynamicSharedMemorySize,
                                       dynBytes);
    if (e == hipSuccess) {
      lstm_scan_lds<<<dim3(GBLK), dim3(NTH), dynBytes, stream>>>(gx, Whh, slots, out);
    } else {
      (void)hipGetLastError();
      lstm_scan_reg<<<dim3(GBLK), dim3(NTH), 0, stream>>>(gx, Whh, slots, out);
    }
  } else {
    zero_out<<<dim3(8), dim3(256), 0, stream>>>(out);
  }
}

// Round 15
// 5786.190 us; speedup vs baseline: 2.8528x; 1.2101x over previous
//
#include <hip/hip_runtime.h>
#include <hip/hip_bf16.h>

#define TT 2048
#define HH 1024
#define GH 4096

__device__ __forceinline__ float sigm(float x){ return 1.0f / (1.0f + __expf(-x)); }
__device__ __forceinline__ float bflo(unsigned v){ return __uint_as_float(v << 16); }
__device__ __forceinline__ float bfhi(unsigned v){ return __uint_as_float(v & 0xffff0000u); }
__device__ __forceinline__ unsigned short f2bu(float x){
  __hip_bfloat16 b = __float2bfloat16(x);
  return *reinterpret_cast<unsigned short*>(&b);
}

// -------- Phase 1: plain fp32 tiled GEMM (validated r3-r14) --------
#define BM 128
#define BN 64
#define BK 32

__global__ __launch_bounds__(256) void gemm_simple(
    const int* __restrict__ tokens,
    const float* __restrict__ emb,
    const float* __restrict__ Wih,
    const float* __restrict__ bih,
    const float* __restrict__ bhh,
    float* __restrict__ gx)
{
  __shared__ float As[BM][BK+1];
  __shared__ float Bs[BN][BK+1];
  __shared__ int tok_s[BM];

  const int tid = threadIdx.x;
  const int bn = blockIdx.x;
  const int bm = blockIdx.y;
  const int m0 = bm*BM, n0 = bn*BN;

  if (tid < BM) tok_s[tid] = tokens[m0 + tid];
  __syncthreads();

  const int tm = tid >> 4;
  const int tn = tid & 15;

  float acc[8][4];
  #pragma unroll
  for (int i = 0; i < 8; ++i)
    #pragma unroll
    for (int j = 0; j < 4; ++j) acc[i][j] = 0.0f;

  for (int k0 = 0; k0 < HH; k0 += BK) {
    for (int idx = tid; idx < BM*BK; idx += 256) {
      int r = idx >> 5, c = idx & 31;
      As[r][c] = emb[(size_t)tok_s[r]*HH + k0 + c];
    }
    for (int idx = tid; idx < BN*BK; idx += 256) {
      int r = idx >> 5, c = idx & 31;
      Bs[r][c] = Wih[(size_t)(n0 + r)*HH + k0 + c];
    }
    __syncthreads();
    #pragma unroll
    for (int k = 0; k < BK; ++k) {
      float a[8], bb[4];
      #pragma unroll
      for (int i = 0; i < 8; ++i) a[i] = As[tm*8 + i][k];
      #pragma unroll
      for (int j = 0; j < 4; ++j) bb[j] = Bs[tn*4 + j][k];
      #pragma unroll
      for (int i = 0; i < 8; ++i)
        #pragma unroll
        for (int j = 0; j < 4; ++j)
          acc[i][j] = fmaf(a[i], bb[j], acc[i][j]);
    }
    __syncthreads();
  }

  float bias[4];
  #pragma unroll
  for (int j = 0; j < 4; ++j) {
    int col = n0 + tn*4 + j;
    bias[j] = bih[col] + bhh[col];
  }
  #pragma unroll
  for (int i = 0; i < 8; ++i) {
    int r = m0 + tm*8 + i;
    #pragma unroll
    for (int j = 0; j < 4; ++j)
      gx[(size_t)r*GH + (n0 + tn*4 + j)] = acc[i][j] + bias[j];
  }
}

// -------- Phase 2: gate-aligned groups + replicated slots --------
// 64 blocks x 512 thr. Group G (32 lanes) owns output o=b*16+G and computes its
// 4 gate rows {g*1024+o}. After full butterfly reduce every lane holds all 4
// gate sums -> in-group activation, lane s==0 publishes IMMEDIATELY (no
// gates_lds, no pre-publish barrier). Slots replicated nrep x: publisher
// writes all replicas, block b polls replica b&(nrep-1) -> 8x fewer pollers
// per MALL line. Self-tagged u64 {tag|h} 2-parity protocol (validated r3==r4).
#define GBLK 64
#define NTH 512
#define HSTRIDE 130
#define ROWU 257          // uint2 units per weight row (256 + 1 pad)

__global__ __launch_bounds__(NTH) void lstm_scan_lds(
    const float* __restrict__ gx,
    const float* __restrict__ Whh,
    unsigned long long* slots,     // [nrep][2][1024] {tag<<32 | fp32 h}
    float* __restrict__ out,       // [2048] fp32 = h ; c
    int nrep)
{
  extern __shared__ __align__(16) unsigned wdw[];   // 64*ROWU uint2 (bf16 weights)
  __shared__ float h_lds[32*HSTRIDE];

  const int b = blockIdx.x;
  const int tid = threadIdx.x;
  const int s  = tid & 31;        // col segment / lane within group
  const int G  = tid >> 5;        // group 0..15 = local output index
  const int o  = (b << 4) + G;    // owned output

  // ---- stage weights once: storage row rsi=G*4+g <- Whh[g*1024 + b*16 + G] ----
  for (int r = 0; r < 64; ++r) {
    const int Gr = r >> 2, g = r & 3;
    const int jrow = (g << 10) + (b << 4) + Gr;
    const int c0 = tid * 2;
    const float2 f2 = *(const float2*)(Whh + (size_t)jrow*HH + c0);
    const unsigned pk = (unsigned)f2bu(f2.x) | ((unsigned)f2bu(f2.y) << 16);
    const int sT = c0 >> 5, j2 = (c0 & 31) >> 2, d = (c0 >> 1) & 1;
    wdw[r*(2*ROWU) + (j2*32 + sT)*2 + d] = pk;
  }
  for (int i = tid; i < 32*HSTRIDE; i += NTH) h_lds[i] = 0.0f;   // h(0)=0

  float cst = 0.0f;               // c state, replicated across the group
  float g4[4];
  #pragma unroll
  for (int g = 0; g < 4; ++g) g4[g] = gx[(g << 10) + o];   // t=0 (uniform/broadcast)

  const int i0 = tid, i1 = tid + 512;
  const int p0 = (i0 >> 5)*HSTRIDE + (i0 & 31);
  const int p1 = (i1 >> 5)*HSTRIDE + (i1 & 31);
  const unsigned long long* prep = slots + (size_t)((b & (nrep-1)) * 2) * 1024;
  __syncthreads();

  const uint2* wld2 = (const uint2*)wdw;

  for (int t = 0; t < TT; ++t) {
    // prefetch next step's gx: HBM latency hides under the poll
    float ng[4] = {0.f, 0.f, 0.f, 0.f};
    if (t + 1 < TT) {
      #pragma unroll
      for (int g = 0; g < 4; ++g)
        ng[g] = gx[(size_t)(t+1)*GH + (g << 10) + o];
    }

    if (t > 0) {
      const unsigned long long* sb = prep + (size_t)(t & 1) * 1024;
      const unsigned tg = (unsigned)t;
      unsigned long long v0 = __hip_atomic_load(&sb[i0], __ATOMIC_RELAXED, __HIP_MEMORY_SCOPE_AGENT);
      unsigned long long v1 = __hip_atomic_load(&sb[i1], __ATOMIC_RELAXED, __HIP_MEMORY_SCOPE_AGENT);
      while ((unsigned)(v0 >> 32) != tg)
        v0 = __hip_atomic_load(&sb[i0], __ATOMIC_RELAXED, __HIP_MEMORY_SCOPE_AGENT);
      while ((unsigned)(v1 >> 32) != tg)
        v1 = __hip_atomic_load(&sb[i1], __ATOMIC_RELAXED, __HIP_MEMORY_SCOPE_AGENT);
      h_lds[p0] = __uint_as_float((unsigned)v0);
      h_lds[p1] = __uint_as_float((unsigned)v1);
      __syncthreads();               // h(t) complete
    }

    // ---- dot: the 4 gates of output o; lane covers cols [s*32, s*32+32) ----
    float a0 = 0.f, a1 = 0.f, a2 = 0.f, a3 = 0.f;
    const float* hseg = h_lds + s*HSTRIDE;
    #pragma unroll
    for (int j2 = 0; j2 < 8; ++j2) {
      const float2 hA = *(const float2*)(hseg + 4*j2);
      const float2 hB = *(const float2*)(hseg + 4*j2 + 2);
      const uint2 w0 = wld2[(G*4 + 0)*ROWU + j2*32 + s];
      const uint2 w1 = wld2[(G*4 + 1)*ROWU + j2*32 + s];
      const uint2 w2 = wld2[(G*4 + 2)*ROWU + j2*32 + s];
      const uint2 w3 = wld2[(G*4 + 3)*ROWU + j2*32 + s];
      a0 = fmaf(bflo(w0.x), hA.x, a0); a0 = fmaf(bfhi(w0.x), hA.y, a0);
      a0 = fmaf(bflo(w0.y), hB.x, a0); a0 = fmaf(bfhi(w0.y), hB.y, a0);
      a1 = fmaf(bflo(w1.x), hA.x, a1); a1 = fmaf(bfhi(w1.x), hA.y, a1);
      a1 = fmaf(bflo(w1.y), hB.x, a1); a1 = fmaf(bfhi(w1.y), hB.y, a1);
      a2 = fmaf(bflo(w2.x), hA.x, a2); a2 = fmaf(bfhi(w2.x), hA.y, a2);
      a2 = fmaf(bflo(w2.y), hB.x, a2); a2 = fmaf(bfhi(w2.y), hB.y, a2);
      a3 = fmaf(bflo(w3.x), hA.x, a3); a3 = fmaf(bfhi(w3.x), hA.y, a3);
      a3 = fmaf(bflo(w3.y), hB.x, a3); a3 = fmaf(bfhi(w3.y), hB.y, a3);
    }
    #pragma unroll
    for (int m = 1; m <= 16; m <<= 1) {    // stays within the 32-lane group
      a0 += __shfl_xor(a0, m);
      a1 += __shfl_xor(a1, m);
      a2 += __shfl_xor(a2, m);
      a3 += __shfl_xor(a3, m);
    }

    // every lane holds all 4 gate sums -> redundant in-group activation
    const float xi = a0 + g4[0];
    const float xf = a1 + g4[1];
    const float xg = a2 + g4[2];
    const float xo = a3 + g4[3];
    cst = sigm(xf)*cst + sigm(xi)*tanhf(xg);
    const float hnew = sigm(xo)*tanhf(cst);

    if (t == TT-1) {
      if (s == 0) {
        out[o]        = hnew;
        out[1024 + o] = cst;
      }
    } else {
      if (s == 0) {                   // publish IMMEDIATELY to all replicas
        const unsigned long long pv =
            (((unsigned long long)(unsigned)(t+1)) << 32) |
            (unsigned long long)__float_as_uint(hnew);
        const int nxt = (t+1) & 1;
        for (int r = 0; r < nrep; ++r)
          __hip_atomic_store(&slots[(size_t)(r*2 + nxt)*1024 + o], pv,
                             __ATOMIC_RELAXED, __HIP_MEMORY_SCOPE_AGENT);
      }
      #pragma unroll
      for (int g = 0; g < 4; ++g) g4[g] = ng[g];
    }
    __syncthreads();                  // protect h_lds before next fill
  }
}

// -------- fallback: exact r7 champion (used only if LDS attribute fails) --------
__global__ __launch_bounds__(NTH, 2) void lstm_scan_reg(
    const float* __restrict__ gx,
    const float* __restrict__ Whh,
    unsigned long long* slots,
    float* __restrict__ out)
{
  const int b = blockIdx.x;
  const int tid = threadIdx.x;
  const int s  = tid & 31;
  const int rg = tid >> 5;

  __shared__ float h_lds[32*HSTRIDE];
  __shared__ float gates_lds[64];

  float w[128];
  #pragma unroll
  for (int a = 0; a < 4; ++a) {
    int row = rg*4 + a;
    int jrow = ((row >> 4) << 10) + (b << 4) + (row & 15);
    const float* wr = Whh + (size_t)jrow*HH + s*32;
    #pragma unroll
    for (int q = 0; q < 8; ++q) {
      float4 f4 = ((const float4*)wr)[q];
      w[a*32 + q*4 + 0] = f4.x; w[a*32 + q*4 + 1] = f4.y;
      w[a*32 + q*4 + 2] = f4.z; w[a*32 + q*4 + 3] = f4.w;
    }
  }

  for (int i = tid; i < 32*HSTRIDE; i += NTH) h_lds[i] = 0.0f;
  float c0 = 0.0f, c1 = 0.0f;
  const int i0 = tid, i1 = tid + 512;
  const int p0 = (i0 >> 5)*HSTRIDE + (i0 & 31);
  const int p1 = (i1 >> 5)*HSTRIDE + (i1 & 31);
  const int myrow = rg*4 + s;
  const int myj = ((myrow >> 4) << 10) + (b << 4) + (myrow & 15);
  __syncthreads();

  for (int t = 0; t < TT; ++t) {
    float gxv = 0.0f;
    if (s < 4) gxv = gx[(size_t)t*GH + myj];

    if (t > 0) {
      const unsigned long long* sb = slots + (size_t)(t & 1)*1024;
      const unsigned tg = (unsigned)t;
      unsigned long long v0 = __hip_atomic_load(&sb[i0], __ATOMIC_RELAXED, __HIP_MEMORY_SCOPE_AGENT);
      unsigned long long v1 = __hip_atomic_load(&sb[i1], __ATOMIC_RELAXED, __HIP_MEMORY_SCOPE_AGENT);
      while ((unsigned)(v0 >> 32) != tg)
        v0 = __hip_atomic_load(&sb[i0], __ATOMIC_RELAXED, __HIP_MEMORY_SCOPE_AGENT);
      while ((unsigned)(v1 >> 32) != tg)
        v1 = __hip_atomic_load(&sb[i1], __ATOMIC_RELAXED, __HIP_MEMORY_SCOPE_AGENT);
      h_lds[p0] = __uint_as_float((unsigned)v0);
      h_lds[p1] = __uint_as_float((unsigned)v1);
      __syncthreads();
    }

    float acc0 = 0.f, acc1 = 0.f, acc2 = 0.f, acc3 = 0.f;
    const float* hseg = h_lds + s*HSTRIDE;
    #pragma unroll
    for (int c2 = 0; c2 < 16; ++c2) {
      float2 hv = *(const float2*)(hseg + 2*c2);
      acc0 = fmaf(w[0*32+2*c2], hv.x, acc0); acc0 = fmaf(w[0*32+2*c2+1], hv.y, acc0);
      acc1 = fmaf(w[1*32+2*c2], hv.x, acc1); acc1 = fmaf(w[1*32+2*c2+1], hv.y, acc1);
      acc2 = fmaf(w[2*32+2*c2], hv.x, acc2); acc2 = fmaf(w[2*32+2*c2+1], hv.y, acc2);
      acc3 = fmaf(w[3*32+2*c2], hv.x, acc3); acc3 = fmaf(w[3*32+2*c2+1], hv.y, acc3);
    }
    #pragma unroll
    for (int m = 1; m <= 16; m <<= 1) {
      acc0 += __shfl_xor(acc0, m);
      acc1 += __shfl_xor(acc1, m);
      acc2 += __shfl_xor(acc2, m);
      acc3 += __shfl_xor(acc3, m);
    }
    if (s < 4) {
      float v = acc0;
      if (s == 1) v = acc1; else if (s == 2) v = acc2; else if (s == 3) v = acc3;
      gates_lds[rg*4 + s] = v + gxv;
    }
    __syncthreads();

    if (tid < 8) {
      int n0 = tid*2, n1 = n0 + 1;
      float xi0 = gates_lds[n0],    xi1 = gates_lds[n1];
      float xf0 = gates_lds[16+n0], xf1 = gates_lds[16+n1];
      float xg0 = gates_lds[32+n0], xg1 = gates_lds[32+n1];
      float xo0 = gates_lds[48+n0], xo1 = gates_lds[48+n1];
      c0 = sigm(xf0)*c0 + sigm(xi0)*tanhf(xg0);
      c1 = sigm(xf1)*c1 + sigm(xi1)*tanhf(xg1);
      float h0 = sigm(xo0)*tanhf(c0);
      float h1 = sigm(xo1)*tanhf(c1);
      if (t == TT-1) {
        out[(b<<4)+n0]      = h0;
        out[(b<<4)+n1]      = h1;
        out[1024+(b<<4)+n0] = c0;
        out[1024+(b<<4)+n1] = c1;
      } else {
        unsigned long long* db = slots + (size_t)((t+1)&1)*1024;
        unsigned long long tg = ((unsigned long long)(unsigned)(t+1)) << 32;
        __hip_atomic_store(&db[(b<<4)+n0], tg | (unsigned long long)__float_as_uint(h0),
                           __ATOMIC_RELAXED, __HIP_MEMORY_SCOPE_AGENT);
        __hip_atomic_store(&db[(b<<4)+n1], tg | (unsigned long long)__float_as_uint(h1),
                           __ATOMIC_RELAXED, __HIP_MEMORY_SCOPE_AGENT);
      }
    }
  }
}

__global__ void zero_out(float* out){
  int i = blockIdx.x*256 + threadIdx.x;
  if (i < 2048) out[i] = 0.0f;
}

extern "C" void kernel_launch(void* const* d_in, const int* in_sizes, int n_in,
                              void* d_out, int out_size, void* d_ws, size_t ws_size,
                              hipStream_t stream) {
  (void)in_sizes; (void)n_in; (void)out_size;
  const int* tokens = (const int*)d_in[0];
  const float* emb  = (const float*)d_in[1];
  const float* Wih  = (const float*)d_in[2];
  const float* Whh  = (const float*)d_in[3];
  const float* bih  = (const float*)d_in[4];
  const float* bhh  = (const float*)d_in[5];
  float* out = (float*)d_out;

  const size_t gxBytes  = (size_t)TT*GH*sizeof(float);
  const size_t repBytes = (size_t)8*2*1024*8;        // 8 replicas
  unsigned long long* slots = (unsigned long long*)d_ws;

  int nrep;
  size_t slotBytes;
  if (ws_size >= repBytes + gxBytes)      { nrep = 8; slotBytes = repBytes; }
  else if (ws_size >= 16384 + gxBytes)    { nrep = 1; slotBytes = 16384;   }
  else {
    zero_out<<<dim3(8), dim3(256), 0, stream>>>(out);
    return;
  }
  float* gx = (float*)((char*)d_ws + slotBytes);

  hipMemsetAsync(slots, 0, slotBytes, stream);
  gemm_simple<<<dim3(64,16), dim3(256), 0, stream>>>(tokens, emb, Wih, bih, bhh, gx);

  const int dynBytes = 64 * (2*ROWU) * 4;   // 131584 B bf16 weight store
  hipError_t e = hipFuncSetAttribute((const void*)lstm_scan_lds,
                                     hipFuncAttributeMaxDynamicSharedMemorySize,
                                     dynBytes);
  if (e == hipSuccess) {
    lstm_scan_lds<<<dim3(GBLK), dim3(NTH), dynBytes, stream>>>(gx, Whh, slots, out, nrep);
  } else {
    (void)hipGetLastError();
    lstm_scan_reg<<<dim3(GBLK), dim3(NTH), 0, stream>>>(gx, Whh, slots, out);
  }
}